// Round 2
// baseline (420.596 us; speedup 1.0000x reference)
//
#include <hip/hip_runtime.h>

// Problem: B=8,N=256,C=512,H=W=8 -> x[8,256,512,64]. All inputs fp32, output fp32.
//
// Algebra (verified): att_i is scalar per (b,n); mean is linear => 3-iter attention
// collapses to m0 = mean(x); scale = s1*s2*s3 recurrence. Grouped linear is linear
// in x and scale is per-row, so
//   out = scale o (y' @ fc_w^T) + (bs @ fc_w^T + fc_b),  y' = x . Ws (unscaled)
// => x (268 MB) read exactly once (K1, HBM floor ~43 us).
//
// R2 change (K1 only): lane remap for line-dense loads. Old layout had 64-lane
// loads at stride 64B = 64 line-requests/instr -> L1-request-bound (~5.3 B/cyc/CU
// at 1 req/cyc < 10.2 needed for HBM peak). New: per instr, lanes 0..31 <-> chan c,
// 32..63 <-> c+1; Ws access is exactly base+lane*16 (16 req), x is 2x256B dense
// (8 req, dup lanes merged). 768 -> 192 req per 4KB payload. K3 byte-identical.

typedef unsigned short u16;
typedef unsigned int u32;
typedef __attribute__((ext_vector_type(8))) short short8;     // 8 bf16 (MFMA A/B frag)
typedef __attribute__((ext_vector_type(4))) float floatx4;
typedef __attribute__((ext_vector_type(2))) unsigned int u32x2;

#define Bb 8
#define Nn 256
#define Cc 512
#define HWs 64
#define BN 2048          // B*N rows
#define DIMd 1024
#define NT 16            // K-tiles of 64 (NT*64 == DIMd)

__device__ __forceinline__ u16 f2bf(float f) {
    u32 u = __builtin_bit_cast(u32, f);
    return (u16)((u + 0x7FFFu + ((u >> 16) & 1u)) >> 16);     // RNE
}

typedef __attribute__((address_space(1))) unsigned int gu32;
typedef __attribute__((address_space(3))) unsigned int lu32;
__device__ __forceinline__ void g2l16(const void* g, void* l) {
    // async global->LDS, 16B per lane; LDS dest is wave-uniform base + lane*16
    __builtin_amdgcn_global_load_lds((gu32*)g, (lu32*)l, 16, 0, 0);
}

// ---------------- K1: fused mean-reduction + grouped Linear(HW,2) + fc_w prep ----
// grid = 2048 blocks (one per (b,n)), 256 threads (4 waves).
// Wave w, pass p, iter i covers channel pair c0 = p*64 + w*16 + i*2 (+cpair):
//   lane = cpair*32 + half*16 + j;  j in [0,16) -> 4-float slice, half -> w0/w1.
// Ws load:  bytes = c0*512 + lane*16            (contiguous 1KB wave access)
// x  load:  bytes = (c0+cpair)*256 + j*16       (2x256B dense; dup lanes merged)
// Blocks 0..255 additionally convert 4 fc_w rows to bf16 and compute bias2.
__global__ __launch_bounds__(256) void k1_fused(
    const float* __restrict__ x, const float* __restrict__ Ws,
    const float* __restrict__ fc_w, const float* __restrict__ bs,
    const float* __restrict__ fc_b,
    u16* __restrict__ ybf, u16* __restrict__ wbf,
    float* __restrict__ bias2, float* __restrict__ m0)
{
    const int bid = blockIdx.x;
    const int tid = threadIdx.x;
    const int w = tid >> 6;
    const int lane = tid & 63;
    const int j = lane & 15;            // 4-float slice within the 64-float row
    const int half = (lane >> 4) & 1;   // 0 -> w0 row, 1 -> w1 row
    const int cpair = lane >> 5;        // which channel of the pair
    const float* xb = x + (size_t)bid * (Cc * HWs);
    float lsum2 = 0.f;                  // every x element counted exactly twice

    for (int p = 0; p < 8; ++p) {
        #pragma unroll
        for (int i = 0; i < 8; ++i) {
            const int c = p * 64 + w * 16 + i * 2 + cpair;
            const floatx4 xv = *(const floatx4*)(xb + (size_t)c * HWs + j * 4);
            const floatx4 wv = *(const floatx4*)(Ws + (size_t)c * 128 + half * 64 + j * 4);
            float d = xv[0] * wv[0] + xv[1] * wv[1] + xv[2] * wv[2] + xv[3] * wv[3];
            lsum2 += xv[0] + xv[1] + xv[2] + xv[3];
            // reduce over the 16-lane group (intra-row-16 -> DPP, full rate)
            d += __shfl_xor(d, 1);
            d += __shfl_xor(d, 2);
            d += __shfl_xor(d, 4);
            d += __shfl_xor(d, 8);
            if (j == 0)                  // 4 lanes: (c0,o0),(c0,o1),(c1,o0),(c1,o1)
                ybf[(size_t)bid * DIMd + c * 2 + half] = f2bf(d);
        }
    }
    // block-wide sum; elements double-counted -> scale by 1/65536
    #pragma unroll
    for (int s = 32; s; s >>= 1) lsum2 += __shfl_xor(lsum2, s);
    __shared__ float wsum[4];
    if (lane == 0) wsum[w] = lsum2;
    __syncthreads();
    if (tid == 0)
        m0[bid] = (wsum[0] + wsum[1] + wsum[2] + wsum[3]) * (1.0f / 65536.f);

    // ---- fused (was k0a+k0b): blocks 0..255, wave w handles column bid*4+w ----
    if (bid < 256) {
        const int wv = bid * 4 + w;        // output col 0..1023
        const floatx4* wp = (const floatx4*)(fc_w + (size_t)wv * DIMd);
        const floatx4* sp = (const floatx4*)bs;    // bs flat [1024]
        u32x2* wo = (u32x2*)(wbf + (size_t)wv * DIMd);
        float s = 0.f;
        #pragma unroll
        for (int v = 0; v < 4; ++v) {
            const int jj = v * 64 + lane;  // coalesced float4 reads + 8B writes
            floatx4 a = wp[jj];
            floatx4 b = sp[jj];
            u32x2 pk;
            pk[0] = (u32)f2bf(a[0]) | ((u32)f2bf(a[1]) << 16);
            pk[1] = (u32)f2bf(a[2]) | ((u32)f2bf(a[3]) << 16);
            wo[jj] = pk;
            s += a[0] * b[0] + a[1] * b[1] + a[2] * b[2] + a[3] * b[3];
        }
        #pragma unroll
        for (int sft = 32; sft; sft >>= 1) s += __shfl_xor(s, sft);
        if (lane == 0) bias2[wv] = s + fc_b[wv];
    }
}

// ---------------- K3: scale recurrence + out = scale o (Ybf @ Wbf^T) + bias2 ------
// grid (32,16) -> 64x64 C-tile; 4 waves, each 32x32 via 2x2 of 16x16x32 MFMA.
// BK=64, double-buffered LDS (32 KB tiles), global_load_lds staging.
// Swizzle: LDS[row][ch] = G[row][ch ^ (row&7)] (16B chunks); reads undo the XOR.
__global__ __launch_bounds__(256) void k3_fused(
    const u16* __restrict__ ybf, const u16* __restrict__ wbf,
    const float* __restrict__ m0, const float* __restrict__ conv_w,
    const float* __restrict__ conv_b, const float* __restrict__ bias2,
    float* __restrict__ out)
{
    __shared__ short8 tiles[2][2][64][8];   // [buf][A/B][row][16B-chunk] = 32 KB
    __shared__ float smA[76], smB[76], sscale[64];

    const int tid = threadIdx.x;
    const int w = tid >> 6, lane = tid & 63, l15 = lane & 15, quad = lane >> 4;
    const int wm = w & 1, wn = w >> 1;
    const int r0 = blockIdx.x * 64, c0 = blockIdx.y * 64;

    // ---- issue stage of K-tile 0 into buffer 0 (async) ----
    #pragma unroll
    for (int r = 0; r < 2; ++r) {
        const int d = r * 256 + tid;               // 16B chunk id 0..511
        const int row = d >> 3, ch = d & 7;
        const int chs = ch ^ (row & 7);            // inverse-swizzled source chunk
        g2l16(ybf + (size_t)(r0 + row) * DIMd + chs * 8, &tiles[0][0][row][ch]);
        g2l16(wbf + (size_t)(c0 + row) * DIMd + chs * 8, &tiles[0][1][row][ch]);
    }

    // ---- fused (was k2): 3x (conv1d k=5 same + sigmoid) scale recurrence ----
    // window n0-6 .. n0+69 (halo 6 shrinks 2/iter); valid centers = n0..n0+63.
    const int bb = r0 >> 8, n0 = r0 & 255;
    const int gn = n0 - 6 + tid;
    float a = 0.f, p = 1.f;
    if (tid < 76) {
        a = (gn >= 0 && gn < Nn) ? m0[bb * Nn + gn] : 0.f;
        smA[tid] = a;
    }
    __syncthreads();
    float* cur = smA; float* nxt = smB;
    for (int i = 0; i < 3; ++i) {
        if (tid < 76) {
            float t = conv_b[i];
            #pragma unroll
            for (int k = 0; k < 5; ++k) {
                const int wk = tid + k - 2;
                const float v = (wk >= 0 && wk < 76) ? cur[wk] : 0.f;
                t += v * conv_w[i * 5 + k];
            }
            const float sg = 1.f / (1.f + __expf(-t));
            p *= sg;
            a = (gn >= 0 && gn < Nn) ? a * sg : 0.f;  // keep zero-padding exact
            nxt[tid] = a;
        }
        __syncthreads();
        float* tmp = cur; cur = nxt; nxt = tmp;
    }
    if (tid >= 6 && tid < 70) sscale[tid - 6] = p;
    // sscale visibility to all waves is covered by the main-loop barriers.

    // ---- main loop: 2-phase double-buffered (T3-minimal) ----
    const int ar = wm * 32 + l15, br = wn * 32 + l15;
    const int sA = ar & 7, sB = br & 7;            // (row+16)&7 == row&7
    floatx4 acc[2][2] = {};
    int cb = 0;
    for (int kt = 0; kt < NT; ++kt) {
        if (kt + 1 < NT) {                         // issue next-tile loads first
            const int nb = cb ^ 1;
            #pragma unroll
            for (int r = 0; r < 2; ++r) {
                const int d = r * 256 + tid;
                const int row = d >> 3, ch = d & 7;
                const int chs = ch ^ (row & 7);
                g2l16(ybf + (size_t)(r0 + row) * DIMd + (kt + 1) * 64 + chs * 8,
                      &tiles[nb][0][row][ch]);
                g2l16(wbf + (size_t)(c0 + row) * DIMd + (kt + 1) * 64 + chs * 8,
                      &tiles[nb][1][row][ch]);
            }
        }
        #pragma unroll
        for (int ks = 0; ks < 2; ++ks) {           // two k-steps of 32 per tile
            const int ca = (quad + ks * 4) ^ sA;
            const int cbk = (quad + ks * 4) ^ sB;
            short8 a0 = tiles[cb][0][ar     ][ca];
            short8 a1 = tiles[cb][0][ar + 16][ca];
            short8 b0 = tiles[cb][1][br     ][cbk];
            short8 b1 = tiles[cb][1][br + 16][cbk];
            acc[0][0] = __builtin_amdgcn_mfma_f32_16x16x32_bf16(a0, b0, acc[0][0], 0, 0, 0);
            acc[0][1] = __builtin_amdgcn_mfma_f32_16x16x32_bf16(a0, b1, acc[0][1], 0, 0, 0);
            acc[1][0] = __builtin_amdgcn_mfma_f32_16x16x32_bf16(a1, b0, acc[1][0], 0, 0, 0);
            acc[1][1] = __builtin_amdgcn_mfma_f32_16x16x32_bf16(a1, b1, acc[1][1], 0, 0, 0);
        }
        __syncthreads();   // drains vmcnt (stage complete) + joins readers
        cb ^= 1;
    }

    // ---- epilogue: scale + bias ----
    #pragma unroll
    for (int ni = 0; ni < 2; ++ni) {
        const int col = c0 + wn * 32 + ni * 16 + l15;
        const float b2 = bias2[col];
        #pragma unroll
        for (int mi = 0; mi < 2; ++mi) {
            #pragma unroll
            for (int r = 0; r < 4; ++r) {
                const int lr = wm * 32 + mi * 16 + quad * 4 + r;
                out[(size_t)(r0 + lr) * DIMd + col] = sscale[lr] * acc[mi][ni][r] + b2;
            }
        }
    }
}

extern "C" void kernel_launch(void* const* d_in, const int* in_sizes, int n_in,
                              void* d_out, int out_size, void* d_ws, size_t ws_size,
                              hipStream_t stream) {
    const float* x      = (const float*)d_in[0];   // [8,256,512,8,8] f32
    const float* conv_w = (const float*)d_in[1];   // [3,5] f32
    const float* conv_b = (const float*)d_in[2];   // [3] f32
    const float* Ws     = (const float*)d_in[3];   // [512,2,64] f32
    const float* bs     = (const float*)d_in[4];   // [512,2] f32
    const float* fc_w   = (const float*)d_in[5];   // [1024,1024] f32
    const float* fc_b   = (const float*)d_in[6];   // [1024] f32
    float* out = (float*)d_out;                    // [8,256,1024] f32

    // workspace: m0[2048] f32 | bias2[1024] f32 | ybf[2048*1024] bf16 | wbf[1024*1024] bf16
    float* m0    = (float*)d_ws;
    float* bias2 = m0 + BN;
    u16*   ybf   = (u16*)(bias2 + DIMd);
    u16*   wbf   = ybf + (size_t)BN * DIMd;

    k1_fused<<<dim3(BN), dim3(256), 0, stream>>>(x, Ws, fc_w, bs, fc_b, ybf, wbf, bias2, m0);
    k3_fused<<<dim3(32, 16), dim3(256), 0, stream>>>(ybf, wbf, m0, conv_w, conv_b, bias2, out);
}

// Round 3
// 394.972 us; speedup vs baseline: 1.0649x; 1.0649x over previous
//
#include <hip/hip_runtime.h>

// Problem: B=8,N=256,C=512,H=W=8 -> x[8,256,512,64]. All inputs fp32, output fp32.
//
// Algebra (verified): att_i is scalar per (b,n); mean is linear => 3-iter attention
// collapses to m0 = mean(x); scale = s1*s2*s3 recurrence. Grouped linear is linear
// in x and scale is per-row, so
//   out = scale o (y' @ fc_w^T) + (bs @ fc_w^T + fc_b),  y' = x . Ws (unscaled)
// => x (268 MB) read exactly once (K1, HBM floor ~43 us).
//
// R3 = exact revert to the R1 397.9us kernel. R2's lane remap regressed +23us:
// post-mortem attributes it to (a) optimizing TA line-requests which were NOT the
// binding constraint (R1's v-unrolled 64B/thread pattern is aggregate-dense and
// HBM-bound), (b) +33% load instrs at half payload, (c) scattered 2-byte stores
// (sub-dword RMW) replacing one coalesced u32 store per pass. Keep R1's pattern:
// per-thread 64B-contiguous x loads, 4-lane-group dot reduction, dword stores.

typedef unsigned short u16;
typedef unsigned int u32;
typedef __attribute__((ext_vector_type(8))) short short8;     // 8 bf16 (MFMA A/B frag)
typedef __attribute__((ext_vector_type(4))) float floatx4;
typedef __attribute__((ext_vector_type(2))) unsigned int u32x2;

#define Bb 8
#define Nn 256
#define Cc 512
#define HWs 64
#define BN 2048          // B*N rows
#define DIMd 1024
#define NT 16            // K-tiles of 64 (NT*64 == DIMd)

__device__ __forceinline__ u16 f2bf(float f) {
    u32 u = __builtin_bit_cast(u32, f);
    return (u16)((u + 0x7FFFu + ((u >> 16) & 1u)) >> 16);     // RNE
}

typedef __attribute__((address_space(1))) unsigned int gu32;
typedef __attribute__((address_space(3))) unsigned int lu32;
__device__ __forceinline__ void g2l16(const void* g, void* l) {
    // async global->LDS, 16B per lane; LDS dest is wave-uniform base + lane*16
    __builtin_amdgcn_global_load_lds((gu32*)g, (lu32*)l, 16, 0, 0);
}

// ---------------- K1: fused mean-reduction + grouped Linear(HW,2) + fc_w prep ----
// grid = 2048 blocks (one per (b,n)), 256 threads.
// Thread t, pass p: channel c = p*64 + (t>>2), quarter q = t&3 handles x[c, q*16..+16).
// x offset = p*4096 + t*16 floats -> 64 B/thread contiguous; the 4-instr v-unroll
// touches every 128B line of the wave's 4KB region exactly once (aggregate-dense).
// Blocks 0..255 additionally convert 4 fc_w rows to bf16 and compute bias2 (one
// wave per output column) -- overlapped with the HBM-bound x stream of other blocks.
__global__ __launch_bounds__(256) void k1_fused(
    const float* __restrict__ x, const float* __restrict__ Ws,
    const float* __restrict__ fc_w, const float* __restrict__ bs,
    const float* __restrict__ fc_b,
    u16* __restrict__ ybf, u16* __restrict__ wbf,
    float* __restrict__ bias2, float* __restrict__ m0)
{
    const int bid = blockIdx.x;
    const int tid = threadIdx.x;
    const float* xb = x + (size_t)bid * (Cc * HWs);
    const int q = tid & 3;
    const int cofs = tid >> 2;
    float lsum = 0.f;

    for (int p = 0; p < 8; ++p) {
        const int c = p * 64 + cofs;
        const floatx4* xp  = (const floatx4*)(xb + p * 4096 + tid * 16);
        const floatx4* w0p = (const floatx4*)(Ws + (size_t)(c * 2 + 0) * HWs + q * 16);
        const floatx4* w1p = (const floatx4*)(Ws + (size_t)(c * 2 + 1) * HWs + q * 16);
        float d0 = 0.f, d1 = 0.f;
        #pragma unroll
        for (int v = 0; v < 4; ++v) {
            floatx4 xv = xp[v];
            floatx4 w0 = w0p[v];
            floatx4 w1 = w1p[v];
            #pragma unroll
            for (int j = 0; j < 4; ++j) {
                d0 += xv[j] * w0[j];
                d1 += xv[j] * w1[j];
                lsum += xv[j];
            }
        }
        d0 += __shfl_xor(d0, 1); d0 += __shfl_xor(d0, 2);
        d1 += __shfl_xor(d1, 1); d1 += __shfl_xor(d1, 2);
        if (q == 0) {
            // pack (d0,d1) -> 2 bf16 in one dword; word index = bid*512 + c
            u32 pk = (u32)f2bf(d0) | ((u32)f2bf(d1) << 16);
            ((u32*)ybf)[(size_t)bid * (DIMd / 2) + c] = pk;
        }
    }
    // block-wide sum for the mean over all 32768 elements of this (b,n)
    #pragma unroll
    for (int s = 32; s; s >>= 1) lsum += __shfl_xor(lsum, s);
    __shared__ float wsum[4];
    if ((tid & 63) == 0) wsum[tid >> 6] = lsum;
    __syncthreads();
    if (tid == 0)
        m0[bid] = (wsum[0] + wsum[1] + wsum[2] + wsum[3]) * (1.0f / 32768.f);

    // ---- fused (was k0a+k0b): blocks 0..255, wave w handles column bid*4+w ----
    if (bid < 256) {
        const int wv = bid * 4 + (tid >> 6);       // output col 0..1023
        const int lane = tid & 63;
        const floatx4* wp = (const floatx4*)(fc_w + (size_t)wv * DIMd);
        const floatx4* sp = (const floatx4*)bs;    // bs flat [1024]
        u32x2* wo = (u32x2*)(wbf + (size_t)wv * DIMd);
        float s = 0.f;
        #pragma unroll
        for (int v = 0; v < 4; ++v) {
            const int j = v * 64 + lane;           // coalesced float4 reads + 8B writes
            floatx4 a = wp[j];
            floatx4 b = sp[j];
            u32x2 pk;
            pk[0] = (u32)f2bf(a[0]) | ((u32)f2bf(a[1]) << 16);
            pk[1] = (u32)f2bf(a[2]) | ((u32)f2bf(a[3]) << 16);
            wo[j] = pk;
            s += a[0] * b[0] + a[1] * b[1] + a[2] * b[2] + a[3] * b[3];
        }
        #pragma unroll
        for (int sft = 32; sft; sft >>= 1) s += __shfl_xor(s, sft);
        if (lane == 0) bias2[wv] = s + fc_b[wv];
    }
}

// ---------------- K3: scale recurrence + out = scale o (Ybf @ Wbf^T) + bias2 ------
// grid (32,16) -> 64x64 C-tile; 4 waves, each 32x32 via 2x2 of 16x16x32 MFMA.
// BK=64, double-buffered LDS (32 KB tiles), global_load_lds staging.
// Swizzle: LDS[row][ch] = G[row][ch ^ (row&7)] (16B chunks); reads undo the XOR.
__global__ __launch_bounds__(256) void k3_fused(
    const u16* __restrict__ ybf, const u16* __restrict__ wbf,
    const float* __restrict__ m0, const float* __restrict__ conv_w,
    const float* __restrict__ conv_b, const float* __restrict__ bias2,
    float* __restrict__ out)
{
    __shared__ short8 tiles[2][2][64][8];   // [buf][A/B][row][16B-chunk] = 32 KB
    __shared__ float smA[76], smB[76], sscale[64];

    const int tid = threadIdx.x;
    const int w = tid >> 6, lane = tid & 63, l15 = lane & 15, quad = lane >> 4;
    const int wm = w & 1, wn = w >> 1;
    const int r0 = blockIdx.x * 64, c0 = blockIdx.y * 64;

    // ---- issue stage of K-tile 0 into buffer 0 (async) ----
    #pragma unroll
    for (int r = 0; r < 2; ++r) {
        const int d = r * 256 + tid;               // 16B chunk id 0..511
        const int row = d >> 3, ch = d & 7;
        const int chs = ch ^ (row & 7);            // inverse-swizzled source chunk
        g2l16(ybf + (size_t)(r0 + row) * DIMd + chs * 8, &tiles[0][0][row][ch]);
        g2l16(wbf + (size_t)(c0 + row) * DIMd + chs * 8, &tiles[0][1][row][ch]);
    }

    // ---- fused (was k2): 3x (conv1d k=5 same + sigmoid) scale recurrence ----
    // window n0-6 .. n0+69 (halo 6 shrinks 2/iter); valid centers = n0..n0+63.
    const int bb = r0 >> 8, n0 = r0 & 255;
    const int gn = n0 - 6 + tid;
    float a = 0.f, p = 1.f;
    if (tid < 76) {
        a = (gn >= 0 && gn < Nn) ? m0[bb * Nn + gn] : 0.f;
        smA[tid] = a;
    }
    __syncthreads();
    float* cur = smA; float* nxt = smB;
    for (int i = 0; i < 3; ++i) {
        if (tid < 76) {
            float t = conv_b[i];
            #pragma unroll
            for (int k = 0; k < 5; ++k) {
                const int wk = tid + k - 2;
                const float v = (wk >= 0 && wk < 76) ? cur[wk] : 0.f;
                t += v * conv_w[i * 5 + k];
            }
            const float sg = 1.f / (1.f + __expf(-t));
            p *= sg;
            a = (gn >= 0 && gn < Nn) ? a * sg : 0.f;  // keep zero-padding exact
            nxt[tid] = a;
        }
        __syncthreads();
        float* tmp = cur; cur = nxt; nxt = tmp;
    }
    if (tid >= 6 && tid < 70) sscale[tid - 6] = p;
    // sscale visibility to all waves is covered by the main-loop barriers.

    // ---- main loop: 2-phase double-buffered (T3-minimal) ----
    const int ar = wm * 32 + l15, br = wn * 32 + l15;
    const int sA = ar & 7, sB = br & 7;            // (row+16)&7 == row&7
    floatx4 acc[2][2] = {};
    int cb = 0;
    for (int kt = 0; kt < NT; ++kt) {
        if (kt + 1 < NT) {                         // issue next-tile loads first
            const int nb = cb ^ 1;
            #pragma unroll
            for (int r = 0; r < 2; ++r) {
                const int d = r * 256 + tid;
                const int row = d >> 3, ch = d & 7;
                const int chs = ch ^ (row & 7);
                g2l16(ybf + (size_t)(r0 + row) * DIMd + (kt + 1) * 64 + chs * 8,
                      &tiles[nb][0][row][ch]);
                g2l16(wbf + (size_t)(c0 + row) * DIMd + (kt + 1) * 64 + chs * 8,
                      &tiles[nb][1][row][ch]);
            }
        }
        #pragma unroll
        for (int ks = 0; ks < 2; ++ks) {           // two k-steps of 32 per tile
            const int ca = (quad + ks * 4) ^ sA;
            const int cbk = (quad + ks * 4) ^ sB;
            short8 a0 = tiles[cb][0][ar     ][ca];
            short8 a1 = tiles[cb][0][ar + 16][ca];
            short8 b0 = tiles[cb][1][br     ][cbk];
            short8 b1 = tiles[cb][1][br + 16][cbk];
            acc[0][0] = __builtin_amdgcn_mfma_f32_16x16x32_bf16(a0, b0, acc[0][0], 0, 0, 0);
            acc[0][1] = __builtin_amdgcn_mfma_f32_16x16x32_bf16(a0, b1, acc[0][1], 0, 0, 0);
            acc[1][0] = __builtin_amdgcn_mfma_f32_16x16x32_bf16(a1, b0, acc[1][0], 0, 0, 0);
            acc[1][1] = __builtin_amdgcn_mfma_f32_16x16x32_bf16(a1, b1, acc[1][1], 0, 0, 0);
        }
        __syncthreads();   // drains vmcnt (stage complete) + joins readers
        cb ^= 1;
    }

    // ---- epilogue: scale + bias ----
    #pragma unroll
    for (int ni = 0; ni < 2; ++ni) {
        const int col = c0 + wn * 32 + ni * 16 + l15;
        const float b2 = bias2[col];
        #pragma unroll
        for (int mi = 0; mi < 2; ++mi) {
            #pragma unroll
            for (int r = 0; r < 4; ++r) {
                const int lr = wm * 32 + mi * 16 + quad * 4 + r;
                out[(size_t)(r0 + lr) * DIMd + col] = sscale[lr] * acc[mi][ni][r] + b2;
            }
        }
    }
}

extern "C" void kernel_launch(void* const* d_in, const int* in_sizes, int n_in,
                              void* d_out, int out_size, void* d_ws, size_t ws_size,
                              hipStream_t stream) {
    const float* x      = (const float*)d_in[0];   // [8,256,512,8,8] f32
    const float* conv_w = (const float*)d_in[1];   // [3,5] f32
    const float* conv_b = (const float*)d_in[2];   // [3] f32
    const float* Ws     = (const float*)d_in[3];   // [512,2,64] f32
    const float* bs     = (const float*)d_in[4];   // [512,2] f32
    const float* fc_w   = (const float*)d_in[5];   // [1024,1024] f32
    const float* fc_b   = (const float*)d_in[6];   // [1024] f32
    float* out = (float*)d_out;                    // [8,256,1024] f32

    // workspace: m0[2048] f32 | bias2[1024] f32 | ybf[2048*1024] bf16 | wbf[1024*1024] bf16
    float* m0    = (float*)d_ws;
    float* bias2 = m0 + BN;
    u16*   ybf   = (u16*)(bias2 + DIMd);
    u16*   wbf   = ybf + (size_t)BN * DIMd;

    k1_fused<<<dim3(BN), dim3(256), 0, stream>>>(x, Ws, fc_w, bs, fc_b, ybf, wbf, bias2, m0);
    k3_fused<<<dim3(32, 16), dim3(256), 0, stream>>>(ybf, wbf, m0, conv_w, conv_b, bias2, out);
}